// Round 12
// baseline (676.754 us; speedup 1.0000x reference)
//
// PaTH attention — r12: flash_split correction loop goes barrier-free —
// E/C MFMA fragments load DIRECT from global (L2-hot via XCD swizzle) with
// an A/B register pipeline; LDS staging + 2 barriers/chunk deleted.
// (r11 lesson from solve_mfma: staging L2-hot per-lane fragments through
// LDS is pure overhead.)
#include <hip/hip_runtime.h>
#include <hip/hip_bf16.h>

typedef __hip_bfloat16 bf16;
typedef unsigned short ushort_t;

#define T_  1024
#define D_  2048
#define H_  32
#define HD_ 64
#define NTRI_ 136   // 16*17/2 lower-triangular tile pairs

static const size_t TT_ = (size_t)T_ * T_;
static const size_t TD_ = (size_t)T_ * D_;

__device__ __forceinline__ ushort_t f2bf(float v) {
    bf16 b = __float2bfloat16(v);
    return *(ushort_t*)&b;
}
__device__ __forceinline__ float bf2f(ushort_t u) {
    bf16 b = *(bf16*)&u;
    return __bfloat162float(b);
}

// decode tri -> (st, tb) with tri = tb*(tb+1)/2 + st, st <= tb
__device__ __forceinline__ void tri_decode(int tri, int& st, int& tb) {
    int t = (int)((sqrtf(8.f * (float)tri + 1.f) - 1.f) * 0.5f);
    if (t * (t + 1) / 2 > tri) t--;
    if ((t + 1) * (t + 2) / 2 <= tri) t++;
    st = tri - t * (t + 1) / 2;
    tb = t;
}

// XCD-aware decode for (NTRI_, NH) grids flattened to 1-D: head z -> XCD z&7
// (MI355X round-robins consecutive blockIdx across 8 XCDs; keeping one head's
// blocks on one XCD makes its 2MB L/C/E panels L2-resident across consumers.)
__device__ __forceinline__ void swz_tri(int bid, int NH, int& tri, int& z) {
    if ((NH & 7) == 0) {
        int xcd = bid & 7, m = bid >> 3;
        z = xcd + 8 * (m / NTRI_);
        tri = m % NTRI_;
    } else {
        z = bid / NTRI_;
        tri = bid % NTRI_;
    }
}

typedef __attribute__((ext_vector_type(8))) short frag8;
typedef __attribute__((ext_vector_type(4))) float f32x4;
typedef __attribute__((ext_vector_type(4))) unsigned short u16x4;
typedef __attribute__((ext_vector_type(8))) unsigned short u16x8;

#define MFMA16(a, b, c) __builtin_amdgcn_mfma_f32_16x16x32_bf16((a), (b), (c), 0, 0, 0)

// ---------------------------------------------------------------------------
// MFMA GEMM: C = A[M,K]bf16 @ Bt[N,K]^T. 128x128 tile, BK=32.
// OUT: 0 = f32 row-major [M,N]
//      3 = packed QKV+small: col<2048 -> qh head-major bf16; <4096 -> kh;
//          <6144 -> vt transposed [head][64][T]; >=6144 -> Cout2 f32 [M][128]
// ---------------------------------------------------------------------------
template <int OUT>
__global__ __launch_bounds__(256) void mfma_gemm(
    const ushort_t* __restrict__ A, const ushort_t* __restrict__ Bt,
    void* __restrict__ Cout, void* __restrict__ Cout2, int M, int N, int K)
{
    __shared__ short Al[128 * 32];
    __shared__ short Bl[128 * 32];
    int tid = threadIdx.x;
    int w = tid >> 6, l = tid & 63;
    int row0 = blockIdx.y * 128, col0 = blockIdx.x * 128;
    int mq = (w >> 1) * 64, nq = (w & 1) * 64;
    int lm = l & 15, kq = l >> 4;
    f32x4 acc[4][4] = {};
    const ushort_t* Ap = A + (size_t)row0 * K;
    const ushort_t* Bp = Bt + (size_t)col0 * K;
    for (int kk = 0; kk < K; kk += 32) {
        __syncthreads();
#pragma unroll
        for (int r = 0; r < 2; r++) {
            int c = r * 256 + w * 64 + l;
            int row = c >> 2, kc = (c & 3) * 8;
            const ushort_t* ga = Ap + (size_t)row * K + kk + kc;
            const ushort_t* gb = Bp + (size_t)row * K + kk + kc;
            short* la = Al + (size_t)(r * 256 + w * 64) * 8;
            short* lb = Bl + (size_t)(r * 256 + w * 64) * 8;
            __builtin_amdgcn_global_load_lds((const __attribute__((address_space(1))) void*)ga,
                                             (__attribute__((address_space(3))) void*)la, 16, 0, 0);
            __builtin_amdgcn_global_load_lds((const __attribute__((address_space(1))) void*)gb,
                                             (__attribute__((address_space(3))) void*)lb, 16, 0, 0);
        }
        __builtin_amdgcn_s_waitcnt(0);
        __syncthreads();
        frag8 af[4], bfg[4];
#pragma unroll
        for (int i = 0; i < 4; i++)
            af[i] = *(const frag8*)&Al[(size_t)(mq + i * 16 + lm) * 32 + kq * 8];
#pragma unroll
        for (int j = 0; j < 4; j++)
            bfg[j] = *(const frag8*)&Bl[(size_t)(nq + j * 16 + lm) * 32 + kq * 8];
#pragma unroll
        for (int i = 0; i < 4; i++)
#pragma unroll
            for (int j = 0; j < 4; j++)
                acc[i][j] = MFMA16(af[i], bfg[j], acc[i][j]);
    }
#pragma unroll
    for (int i = 0; i < 4; i++)
#pragma unroll
        for (int j = 0; j < 4; j++)
#pragma unroll
            for (int r = 0; r < 4; r++) {
                int row = row0 + mq + i * 16 + kq * 4 + r;
                int col = col0 + nq + j * 16 + lm;
                float v = acc[i][j][r];
                if (OUT == 0) {
                    ((float*)Cout)[(size_t)row * N + col] = v;
                } else {
                    ushort_t* q = (ushort_t*)Cout;
                    int which = col >> 11, cl = col & 2047;
                    int hd = cl >> 6, d = cl & 63;
                    if (which == 0)
                        q[((size_t)hd * M + row) * 64 + d] = f2bf(v);
                    else if (which == 1)
                        q[(size_t)M * 2048 + ((size_t)hd * M + row) * 64 + d] = f2bf(v);
                    else if (which == 2)
                        q[(size_t)M * 4096 + ((size_t)hd * 64 + d) * M + row] = f2bf(v);
                    else
                        ((float*)Cout2)[(size_t)row * 128 + (col - 6144)] = v;
                }
            }
}

// ---------------------------------------------------------------------------
__global__ void transpose_convert(const float* __restrict__ W, ushort_t* __restrict__ Wt,
                                  int R, int Cc)
{
    __shared__ float tile[32][33];
    int bx = blockIdx.x * 32, by = blockIdx.y * 32;
    int tx = threadIdx.x, ty = threadIdx.y;
    for (int i = ty; i < 32; i += 8)
        tile[i][tx] = W[(size_t)(by + i) * Cc + bx + tx];
    __syncthreads();
    for (int i = ty; i < 32; i += 8)
        Wt[(size_t)(bx + i) * R + by + tx] = f2bf(tile[tx][i]);
}

// pack Ww1^T/Wbt^T/Wg^T (+zero pad) into rows [0..128) of dst[128][2048]
__global__ void pack96(const float* __restrict__ Ww1, const float* __restrict__ Wbt,
                       const float* __restrict__ Wg, ushort_t* __restrict__ dst)
{
    int r = blockIdx.x;
    int k = blockIdx.y * 256 + threadIdx.x;
    float v = 0.f;
    if (r < 32)       v = Ww1[(size_t)k * 32 + r];
    else if (r < 64)  v = Wbt[(size_t)k * 32 + (r - 32)];
    else if (r < 96)  v = Wg[(size_t)k * 32 + (r - 64)];
    dst[(size_t)r * 2048 + k] = f2bf(v);
}

__global__ void convert_bf16(const float* __restrict__ in, ushort_t* __restrict__ out, int n)
{
    int i = blockIdx.x * 256 + threadIdx.x;
    if (i < n) out[i] = f2bf(in[i]);
}

// epilogue of the 96-proj: w1 bf16, beta, G(pre-scan)
__global__ void bg96(const float* __restrict__ s96, const float* __restrict__ bbt,
                     const float* __restrict__ bgp, ushort_t* __restrict__ w1bf,
                     float* __restrict__ betaB, float* __restrict__ Gb)
{
    int idx = blockIdx.x * 256 + threadIdx.x;   // over T_*128
    int t = idx >> 7, o = idx & 127;
    if (o >= 96) return;
    float v = s96[(size_t)t * 128 + o];
    if (o < 32) {
        w1bf[(size_t)t * 32 + o] = f2bf(v);
    } else if (o < 64) {
        float xb = v + bbt[o - 32];
        betaB[(size_t)t * H_ + (o - 32)] = 2.f / (1.f + expf(-xb));
    } else {
        float xg = v + bgp[o - 64];
        Gb[(size_t)t * H_ + (o - 64)] =
            (xg >= 0.f) ? -log1pf(expf(-xg)) : (xg - log1pf(expf(xg)));
    }
}

// parallel inclusive scan of G[:, h] per head. Grid (H_), block 256.
__global__ void scan_g(float* __restrict__ G)
{
    int h = blockIdx.x;
    int tid = threadIdx.x;
    __shared__ float psum[256];
    float v[4];
    float s = 0.f;
#pragma unroll
    for (int r = 0; r < 4; r++) {
        v[r] = G[(size_t)(tid * 4 + r) * H_ + h];
        s += v[r];
    }
    psum[tid] = s;
    __syncthreads();
    for (int off = 1; off < 256; off <<= 1) {
        float t = (tid >= off) ? psum[tid - off] : 0.f;
        __syncthreads();
        psum[tid] += t;
        __syncthreads();
    }
    float run = (tid > 0) ? psum[tid - 1] : 0.f;
#pragma unroll
    for (int r = 0; r < 4; r++) {
        run += v[r];
        G[(size_t)(tid * 4 + r) * H_ + h] = run;
    }
}

// conv(3) + silu + l2norm -> wh bf16 head-major [H][T][64]
__global__ void conv_silu_norm(const float* __restrict__ wr, const float* __restrict__ convw,
                               ushort_t* __restrict__ wh)
{
    int b = blockIdx.x;
    int t = b >> 5, h = b & 31;
    int d = threadIdx.x;
    int c = h * 64 + d;
    float c0 = convw[c * 3 + 0];
    float c1 = convw[c * 3 + 1];
    float c2 = convw[c * 3 + 2];
    float x = c2 * wr[(size_t)t * D_ + c];
    if (t >= 1) x += c1 * wr[(size_t)(t - 1) * D_ + c];
    if (t >= 2) x += c0 * wr[(size_t)(t - 2) * D_ + c];
    float y = x / (1.f + expf(-x));
    float ss = y * y;
    for (int off = 32; off > 0; off >>= 1) ss += __shfl_xor(ss, off, 64);
    wh[((size_t)h * T_ + t) * 64 + d] = f2bf(y * rsqrtf(ss));
}

// ---------------------------------------------------------------------------
// pairdotLC: per lower tile (t0,s0):
//   L[t][s]  = strict(w_t.w_s)*beta[s]   (bf16 row-major, into ELb)
//   Ct[s][t] = strict(w_t.k_s)           (bf16 TRANSPOSED [s][t])
// Grid (NTRI_*NH) 1-D, XCD-swizzled.
// ---------------------------------------------------------------------------
__global__ __launch_bounds__(256) void pairdotLC(
    const ushort_t* __restrict__ kh, const ushort_t* __restrict__ wh,
    const float* __restrict__ betaB,
    ushort_t* __restrict__ ELb, ushort_t* __restrict__ Ct, int hs, int NH)
{
    int st, tb, tri, z;
    swz_tri(blockIdx.x, NH, tri, z);
    tri_decode(tri, st, tb);
    int s0 = st * 64, t0 = tb * 64;
    int head = hs + z;
    const ushort_t* kb = kh + (size_t)head * T_ * 64;
    const ushort_t* wb = wh + (size_t)head * T_ * 64;
    ushort_t* Lz = ELb + (size_t)z * TT_;
    ushort_t* Cz = Ct + (size_t)z * TT_;
    int tid = threadIdx.x;
    int w = tid >> 6, l = tid & 63;
    int lm = l & 15, kq = l >> 4;
    int rowA = t0 + w * 16 + lm;
    f32x4 accL[4] = {}, accS[4] = {};
#pragma unroll
    for (int kk = 0; kk < 64; kk += 32) {
        frag8 aw = *(const frag8*)&wb[(size_t)rowA * 64 + kk + kq * 8];
#pragma unroll
        for (int j = 0; j < 4; j++) {
            int colr = s0 + j * 16 + lm;
            frag8 bw = *(const frag8*)&wb[(size_t)colr * 64 + kk + kq * 8];
            frag8 bk = *(const frag8*)&kb[(size_t)colr * 64 + kk + kq * 8];
            accL[j] = MFMA16(aw, bw, accL[j]);
            accS[j] = MFMA16(aw, bk, accS[j]);
        }
    }
    int m0 = w * 16 + kq * 4;
#pragma unroll
    for (int j = 0; j < 4; j++) {
        int s = s0 + j * 16 + lm;
        float beta = betaB[(size_t)s * H_ + head];
        ushort_t cl[4];
#pragma unroll
        for (int r = 0; r < 4; r++) {
            int t = t0 + m0 + r;
            Lz[(size_t)t * T_ + s] = f2bf((s < t) ? accL[j][r] * beta : 0.f);
            cl[r] = f2bf((s < t) ? accS[j][r] : 0.f);
        }
        *(u16x4*)&Cz[(size_t)s * T_ + t0 + m0] = *(u16x4*)cl;
    }
}

// pairdotE: Em[t][s] = -causal(q_t.w_s)*beta[s] into ELb (L dead post-solve)
// Grid (NTRI_*NH) 1-D, XCD-swizzled.
__global__ __launch_bounds__(256) void pairdotE(
    const ushort_t* __restrict__ qh, const ushort_t* __restrict__ wh,
    const float* __restrict__ betaB, ushort_t* __restrict__ ELb, int hs, int NH)
{
    int st, tb, tri, z;
    swz_tri(blockIdx.x, NH, tri, z);
    tri_decode(tri, st, tb);
    int s0 = st * 64, t0 = tb * 64;
    int head = hs + z;
    const ushort_t* qb = qh + (size_t)head * T_ * 64;
    const ushort_t* wb = wh + (size_t)head * T_ * 64;
    ushort_t* Ez = ELb + (size_t)z * TT_;
    int tid = threadIdx.x;
    int w = tid >> 6, l = tid & 63;
    int lm = l & 15, kq = l >> 4;
    int rowA = t0 + w * 16 + lm;
    f32x4 accE[4] = {};
#pragma unroll
    for (int kk = 0; kk < 64; kk += 32) {
        frag8 aq = *(const frag8*)&qb[(size_t)rowA * 64 + kk + kq * 8];
#pragma unroll
        for (int j = 0; j < 4; j++) {
            frag8 bw = *(const frag8*)&wb[(size_t)(s0 + j * 16 + lm) * 64 + kk + kq * 8];
            accE[j] = MFMA16(aq, bw, accE[j]);
        }
    }
    int m0 = w * 16 + kq * 4;
#pragma unroll
    for (int j = 0; j < 4; j++) {
        int s = s0 + j * 16 + lm;
        float beta = betaB[(size_t)s * H_ + head];
#pragma unroll
        for (int r = 0; r < 4; r++) {
            int t = t0 + m0 + r;
            Ez[(size_t)t * T_ + s] = f2bf((s <= t) ? -accE[j][r] * beta : 0.f);
        }
    }
}

// ---------------------------------------------------------------------------
// diag_inv: invert 64x64 unit-lower diag blocks of (I + L); Minv bf16 out.
// Column-sweep forward substitution, fully unrolled so each thread's column
// x[64] lives in VGPRs. Grid (16, NH), block 64.
// ---------------------------------------------------------------------------
__global__ void diag_inv(const ushort_t* __restrict__ Lb, ushort_t* __restrict__ Minv)
{
    int bi = blockIdx.x, z = blockIdx.y;
    const ushort_t* Lh = Lb + (size_t)z * TT_;
    __shared__ float NbT[64][65];      // NbT[c][r] = N[r][c]
    int j = threadIdx.x;
    for (int i = j; i < 4096; i += 64) {
        int r = i >> 6, c = i & 63;    // c == j: coalesced row reads
        NbT[c][r] = (c < r) ? bf2f(Lh[(size_t)(bi * 64 + r) * T_ + bi * 64 + c]) : 0.f;
    }
    __syncthreads();
    // column j of X = (I+N)^{-1}:  x[t] = d(t,j) - sum_{i<t} N[t][i] x[i]
    float x[64];
#pragma unroll
    for (int t = 0; t < 64; t++) x[t] = (t == j) ? 1.f : 0.f;
#pragma unroll
    for (int i = 0; i < 63; i++) {
        float xi = x[i];
#pragma unroll
        for (int t = i + 1; t < 64; t++) x[t] -= NbT[i][t] * xi;
    }
    ushort_t* Mo = Minv + ((size_t)z * 16 + bi) * 4096;
#pragma unroll
    for (int t = 0; t < 64; t++) Mo[t * 64 + j] = f2bf(x[t]);   // coalesced
}

// ---------------------------------------------------------------------------
// solve_mfma: block-forward solve for one 64-col strip, C-resident-in-LDS,
// L A-fragments DIRECT FROM GLOBAL (L2-hot via XCD swizzle), 4-deep register
// pipeline, no barriers in the K-loop (2/step around the Xbt round-trip).
// Grid (16*NH) 1-D, block 256. LDS = 132 + 9 = 141KB (1 block/CU).
// ---------------------------------------------------------------------------
__global__ __launch_bounds__(256) void solve_mfma(
    ushort_t* __restrict__ Ct, const ushort_t* __restrict__ Lb,
    const ushort_t* __restrict__ Minv, int NH)
{
    int bid = blockIdx.x;
    int ct, z;
    if ((NH & 7) == 0) {
        int xcd = bid & 7, m = bid >> 3, nh8 = NH >> 3;
        z = xcd + 8 * (m % nh8);
        ct = m / nh8;
    } else {
        z = bid % NH;
        ct = bid / NH;
    }
    ushort_t* Cz = Ct + (size_t)z * TT_;
    const ushort_t* Lz = Lb + (size_t)z * TT_;
    __shared__ ushort_t Cs[64][1032];   // strip's C panel, abs-col indexed, +8 pad
    __shared__ ushort_t Xbt[64][72];
    int tid = threadIdx.x;
    int w = tid >> 6, l = tid & 63;
    int lm = l & 15, kq = l >> 4;
    int s0 = ct * 64;
    int m0 = w * 16 + kq * 4;

    // DMA the strip's C rows into LDS, 1024B segments, cols >= 512*(s0>>9)
    {
        int h0 = s0 >> 9, segs = 2 - h0;
        for (int sg = w; sg < 64 * segs; sg += 4) {
            int r, hh;
            if (segs == 2) { r = sg >> 1; hh = sg & 1; }
            else           { r = sg;      hh = 1;      }
            const ushort_t* ga = Cz + (size_t)(s0 + r) * T_ + hh * 512 + l * 8;
            ushort_t* la = &Cs[r][hh * 512];
            __builtin_amdgcn_global_load_lds((const __attribute__((address_space(1))) void*)ga,
                                             (__attribute__((address_space(3))) void*)la, 16, 0, 0);
        }
    }
    __builtin_amdgcn_s_waitcnt(0);
    __syncthreads();

    for (int bi = ct; bi < 16; bi++) {
        int kend = bi * 64;   // also the L block-row base for this step
        const ushort_t* Lrow = Lz + (size_t)(kend + w * 16 + lm) * T_ + kq * 8;
        auto loadL = [&](int idx) -> frag8 {
            return *(const frag8*)&Lrow[s0 + idx * 32];
        };
        f32x4 acc[4] = {};
        auto mfma4 = [&](frag8 a, int idx) {
            int kk = s0 + idx * 32;
#pragma unroll
            for (int j = 0; j < 4; j++) {
                frag8 b = *(const frag8*)&Cs[j * 16 + lm][kk + kq * 8];
                acc[j] = MFMA16(a, b, acc[j]);
            }
        };

        const ushort_t* Mo = Minv + ((size_t)z * 16 + bi) * 4096;
        frag8 ma0 = *(const frag8*)&Mo[(size_t)(w * 16 + lm) * 64 + kq * 8];
        frag8 ma1 = *(const frag8*)&Mo[(size_t)(w * 16 + lm) * 64 + 32 + kq * 8];
        u16x4 rhs[4];
#pragma unroll
        for (int j = 0; j < 4; j++)
            rhs[j] = *(const u16x4*)&Cs[j * 16 + lm][kend + m0];

        // K-loop: nk = 2*(bi-ct) chunks of 32, 4-deep register pipeline,
        // no barriers (reads Cs cols<kend; writes this step go to col bi).
        int nk = (kend - s0) >> 5;
        frag8 p0, p1, p2, p3;
        if (nk > 0) p0 = loadL(0);
        if (nk > 1) p1 = loadL(1);
        if (nk > 2) p2 = loadL(2);
        if (nk > 3) p3 = loadL(3);
        int i = 0;
        for (; i + 4 <= nk; i += 4) {
            frag8 c0 = p0, c1 = p1, c2 = p2, c3 = p3;
            if (i + 4 < nk) p0 = loadL(i + 4);
            if (i + 5 < nk) p1 = loadL(i + 5);
            if (i + 6 < nk) p2 = loadL(i + 6);
            if (i + 7 < nk) p3 = loadL(i + 7);
            mfma4(c0, i); mfma4(c1, i + 1); mfma4(c2, i + 2); mfma4(c3, i + 3);
        }
        if (i < nk) {       // tail of 2 (nk is even)
            mfma4(p0, i);
            mfma4(p1, i + 1);
        }

        // epilogue: X = rhs - acc -> Xbt; res = Minv_diag @ X -> Cs col bi
#pragma unroll
        for (int j = 0; j < 4; j++) {
            ushort_t xb[4];
#pragma unroll
            for (int r = 0; r < 4; r++) xb[r] = f2bf(bf2f(rhs[j][r]) - acc[j][r]);
            *(u16x4*)&Xbt[j * 16 + lm][m0] = *(u16x4*)xb;
        }
        __syncthreads();                       // Xbt writes visible
        f32x4 res[4] = {};
#pragma unroll
        for (int j = 0; j < 4; j++) {
            frag8 b0 = *(const frag8*)&Xbt[j * 16 + lm][kq * 8];
            frag8 b1 = *(const frag8*)&Xbt[j * 16 + lm][32 + kq * 8];
            res[j] = MFMA16(ma0, b0, res[j]);
            res[j] = MFMA16(ma1, b1, res[j]);
        }
#pragma unroll
        for (int j = 0; j < 4; j++) {
            ushort_t cr[4];
#pragma unroll
            for (int r = 0; r < 4; r++) cr[r] = f2bf(res[j][r]);
            *(u16x4*)&Cs[j * 16 + lm][kend + m0] = *(u16x4*)cr;
        }
        __syncthreads();   // Cs col-bi + Xbt reuse ordered for next step
    }

    // writeback cols [s0, 1024) of the strip
    int nW = (1024 - s0) >> 3;
    for (int i = tid; i < 64 * nW; i += 256) {
        int r = i / nW, c = (i - r * nW) * 8;
        *(u16x8*)&Cz[(size_t)(s0 + r) * T_ + s0 + c] = *(const u16x8*)&Cs[r][s0 + c];
    }
}

// ---------------------------------------------------------------------------
// flash_split: one triangular (s-tile, t-tile, head) per block.
//   x = q.k^T + sum_k Em[t,k] C[k,s]; single-tile softmax partial -> Op/ml.
// ALL MFMA fragments (q/K/V/E/C) direct from global; E/C A/B register
// pipeline; zero __syncthreads (Pl slab is per-wave). LDS = Pl only (9.7KB).
// Grid (NTRI_*NH) 1-D, XCD-swizzled, block 256.
// ---------------------------------------------------------------------------
__global__ __launch_bounds__(256) void flash_split(
    const ushort_t* __restrict__ qh, const ushort_t* __restrict__ kh,
    const ushort_t* __restrict__ vt, const ushort_t* __restrict__ Em,
    const ushort_t* __restrict__ Ct, const float* __restrict__ Gb,
    ushort_t* __restrict__ Op, float* __restrict__ ml, int hs, int NH)
{
    int st, tb, tri, z;
    swz_tri(blockIdx.x, NH, tri, z);
    tri_decode(tri, st, tb);
    int t0 = tb * 64, s0 = st * 64;
    int head = hs + z;
    const ushort_t* qb = qh + (size_t)head * T_ * 64;
    const ushort_t* kb = kh + (size_t)head * T_ * 64;
    const ushort_t* vb = vt + (size_t)head * 64 * T_;
    const ushort_t* Ez = Em + (size_t)z * TT_;
    const ushort_t* Cz = Ct + (size_t)z * TT_;
    __shared__ ushort_t Pl[4][16][76];
    int tid = threadIdx.x;
    int w = tid >> 6, l = tid & 63;
    int lm = l & 15, kq = l >> 4;
    int rowA = t0 + w * 16 + lm;
    int m0 = w * 16 + kq * 4;

    // per-lane base rows for E (A-operand) and C (B-operand) fragments
    const ushort_t* Erow = Ez + (size_t)rowA * T_ + kq * 8;
    auto loadE = [&](int kc, frag8& a0, frag8& a1) {
        a0 = *(const frag8*)&Erow[kc];
        a1 = *(const frag8*)&Erow[kc + 32];
    };
    auto loadC = [&](int kc, frag8 (&b0)[4], frag8 (&b1)[4]) {
#pragma unroll
        for (int j = 0; j < 4; j++) {
            const ushort_t* cr = Cz + (size_t)(s0 + j * 16 + lm) * T_ + kc + kq * 8;
            b0[j] = *(const frag8*)cr;
            b1[j] = *(const frag8*)(cr + 32);
        }
    };

    // prefetch chunk 0 of E/C so latency hides under QK^T
    frag8 ea0A, ea1A, cb0A[4], cb1A[4];
    frag8 ea0B, ea1B, cb0B[4], cb1B[4];
    loadE(s0, ea0A, ea1A);
    loadC(s0, cb0A, cb1A);

    // q and K fragments direct from global
    frag8 aq0 = *(const frag8*)&qb[(size_t)rowA * 64 + kq * 8];
    frag8 aq1 = *(const frag8*)&qb[(size_t)rowA * 64 + 32 + kq * 8];
    f32x4 x[4] = {};
#pragma unroll
    for (int j = 0; j < 4; j++) {
        frag8 b0 = *(const frag8*)&kb[(size_t)(s0 + j * 16 + lm) * 64 + kq * 8];
        frag8 b1 = *(const frag8*)&kb[(size_t)(s0 + j * 16 + lm) * 64 + 32 + kq * 8];
        x[j] = MFMA16(aq0, b0, x[j]);
        x[j] = MFMA16(aq1, b1, x[j]);
    }

    // correction: x += sum over k-chunks of Em(t,k) * C(k,s)
    // A/B register pipeline, no LDS, no barriers.
    int nc = tb - st + 1;
    int ci = 0;
    for (;;) {
        if (ci + 1 < nc) { loadE(s0 + (ci + 1) * 64, ea0B, ea1B);
                           loadC(s0 + (ci + 1) * 64, cb0B, cb1B); }
#pragma unroll
        for (int j = 0; j < 4; j++) {
            x[j] = MFMA16(ea0A, cb0A[j], x[j]);
            x[j] = MFMA16(ea1A, cb1A[j], x[j]);
        }
        ci++;
        if (ci >= nc) break;
        if (ci + 1 < nc) { loadE(s0 + (ci + 1) * 64, ea0A, ea1A);
                           loadC(s0 + (ci + 1) * 64, cb0A, cb1A); }
#pragma unroll
        for (int j = 0; j < 4; j++) {
            x[j] = MFMA16(ea0B, cb0B[j], x[j]);
            x[j] = MFMA16(ea1B, cb1B[j], x[j]);
        }
        ci++;
        if (ci >= nc) break;
    }

    // V fragments direct from global; latency hides under softmax VALU
    frag8 vf0[4], vf1[4];
#pragma unroll
    for (int j = 0; j < 4; j++) {
        vf0[j] = *(const frag8*)&vb[(size_t)(j * 16 + lm) * T_ + s0 + kq * 8];
        vf1[j] = *(const frag8*)&vb[(size_t)(j * 16 + lm) * T_ + s0 + 32 + kq * 8];
    }

    // single-tile softmax partial
    float lg[4][4];
#pragma unroll
    for (int j = 0; j < 4; j++) {
        int s = s0 + j * 16 + lm;
        float g = Gb[(size_t)s * H_ + head];
#pragma unroll
        for (int r = 0; r < 4; r++) {
            int t = t0 + m0 + r;
            lg[j][r] = (s <= t) ? (x[j][r] * 0.125f - g) : -1e30f;
        }
    }
    float mrow[4];
#pragma unroll
    for (int r = 0; r < 4; r++)
        mrow[r] = fmaxf(fmaxf(lg[0][r], lg[1][r]), fmaxf(lg[2][r], lg[3][r]));
#pragma unroll
    for (int d = 1; d < 16; d <<= 1)
#pragma unroll
        for (int r = 0; r < 4; r++) mrow[r] = fmaxf(mrow[r], __shfl_xor(mrow[r], d, 64));
    float lrow[4] = {0.f, 0.f, 0.f, 0.f};
#pragma unroll
    for (int j = 0; j < 4; j++)
#pragma unroll
        for (int r = 0; r < 4; r++) {
            float p = __expf(lg[j][r] - mrow[r]);
            lg[j][r] = p;
            lrow[r] += p;
        }
#pragma unroll
    for (int d = 1; d < 16; d <<= 1)
#pragma unroll
        for (int r = 0; r < 4; r++) lrow[r] += __shfl_xor(lrow[r], d, 64);
    // P -> per-wave slab (same-wave ordering, no barrier), O = P @ V
#pragma unroll
    for (int j = 0; j < 4; j++)
#pragma unroll
        for (int r = 0; r < 4; r++)
            Pl[w][kq * 4 + r][j * 16 + lm] = f2bf(lg[j][r]);
    f32x4 o[4] = {};
#pragma unroll
    for (int j = 0; j < 4; j++) {
        frag8 a0 = *(const frag8*)&Pl[w][lm][kq * 8];
        frag8 a1 = *(const frag8*)&Pl[w][lm][32 + kq * 8];
        o[j] = MFMA16(a0, vf0[j], o[j]);
        o[j] = MFMA16(a1, vf1[j], o[j]);
    }
    size_t pbase = ((size_t)z * NTRI_ + tri) * 4096;
#pragma unroll
    for (int j = 0; j < 4; j++)
#pragma unroll
        for (int r = 0; r < 4; r++)
            Op[pbase + (size_t)(m0 + r) * 64 + j * 16 + lm] = f2bf(o[j][r]);
    if (lm == 0) {
        size_t mbase = ((size_t)z * NTRI_ + tri) * 128;
#pragma unroll
        for (int r = 0; r < 4; r++) {
            ml[mbase + m0 + r] = mrow[r];
            ml[mbase + 64 + m0 + r] = lrow[r];
        }
    }
}

// ---------------------------------------------------------------------------
// combine: merge <=16 partials per (t-tile, head) -> of bf16.
// ---------------------------------------------------------------------------
__global__ __launch_bounds__(256) void combine(
    const ushort_t* __restrict__ Op, const float* __restrict__ ml,
    ushort_t* __restrict__ of, int hs)
{
    int tb = blockIdx.x, z = blockIdx.y;
    int head = hs + z;
    int tid = threadIdx.x;
    int row = tid >> 2, cg = (tid & 3) * 16;
    size_t pb0 = (size_t)z * NTRI_ + (size_t)tb * (tb + 1) / 2;
    float M = -1e30f;
    for (int st = 0; st <= tb; st++)
        M = fmaxf(M, ml[(pb0 + st) * 128 + row]);
    float acc[16] = {};
    float lsum = 0.f;
    for (int st = 0; st <= tb; st++) {
        float mp = ml[(pb0 + st) * 128 + row];
        float lp = ml[(pb0 + st) * 128 + 64 + row];
        float sc = __expf(mp - M);
        lsum += lp * sc;
        const ushort_t* op = Op + (pb0 + st) * 4096 + (size_t)row * 64 + cg;
#pragma unroll
        for (int i = 0; i < 16; i++) acc[i] += bf2f(op[i]) * sc;
    }
    float inv = 1.f / lsum;
    int t = tb * 64 + row;
    ushort_t* dst = of + (size_t)t * D_ + (size_t)head * 64 + cg;
#pragma unroll
    for (int i = 0; i < 16; i++) dst[i] = f2bf(acc[i] * inv);
}

// ---------------------------------------------------------------------------
extern "C" void kernel_launch(void* const* d_in, const int* in_sizes, int n_in,
                              void* d_out, int out_size, void* d_ws, size_t ws_size,
                              hipStream_t stream)
{
    const float* h     = (const float*)d_in[0];
    const float* Wq    = (const float*)d_in[1];
    const float* Wk    = (const float*)d_in[2];
    const float* Wv    = (const float*)d_in[3];
    const float* Ww1   = (const float*)d_in[4];
    const float* Ww2   = (const float*)d_in[5];
    const float* convw = (const float*)d_in[6];
    const float* Wbt   = (const float*)d_in[7];
    const float* bbt   = (const float*)d_in[8];
    const float* Wg    = (const float*)d_in[9];
    const float* bgp   = (const float*)d_in[10];
    const float* Wo    = (const float*)d_in[11];
    float* out = (float*)d_out;

    float* ws = (float*)d_ws;
    size_t off = 0;
    auto allocF = [&](size_t nf) { float* p = ws + off; off += (nf + 1023) & ~(size_t)1023; return p; };

    // ---- persistent region (lives across the whole launch) ----
    float*    betaB = allocF((size_t)T_ * H_);
    float*    Gb    = allocF((size_t)T_ * H_);
    ushort_t* h_bf  = (ushort_t*)allocF(TD_ / 2);   // reused as of_bf after QKV GEMM
    ushort_t* of_bf = h_bf;
    ushort_t* w1bf  = (ushort_t*)allocF((size_t)T_ * 32 / 2);
    ushort_t* Ww2t  = (ushort_t*)allocF((size_t)D_ * 32 / 2);
    ushort_t* qkv   = (ushort_t*)allocF((size_t)3 * TD_ / 2);
    ushort_t* qh    = qkv;
    ushort_t* kh    = qkv + TD_;
    ushort_t* vt    = qkv + 2 * TD_;
    ushort_t* wh    = (ushort_t*)allocF(TD_ / 2);

    size_t scrOff = off;            // start of the overlaid scratch region
    size_t capF = ws_size / 4;

    // ---- phase A scratch (projection prep; dead before the chunk loop) ----
    float*    wr  = allocF(TD_);
    float*    s96 = allocF((size_t)T_ * 128);
    ushort_t* Wtc = (ushort_t*)allocF((size_t)6272 * D_ / 2);   // QKV + 96-pack

    // ---- phase B scratch overlays phase A (per-head chunk buffers) ----
    int NH = 32;
    ushort_t *ELb, *Ct, *OpB, *Mv;
    float* mlB;
    for (;;) {
        off = scrOff;
        ELb = (ushort_t*)allocF((size_t)NH * TT_ / 2);            // L, then Em
        Ct  = (ushort_t*)allocF((size_t)NH * TT_ / 2);
        OpB = (ushort_t*)allocF((size_t)NH * NTRI_ * 4096 / 2);   // triangular partials
        Mv  = (ushort_t*)allocF((size_t)NH * 16 * 4096 / 2);
        mlB = allocF((size_t)NH * NTRI_ * 128);
        if (off <= capF || NH == 1) break;
        NH >>= 1;
    }

    // ---- phase C scratch: Wo^T overlays phase B (all per-head dead) ----
    ushort_t* WoT = (ushort_t*)(ws + scrOff);

    dim3 blk(256);
    dim3 tcvB(32, 8);
    dim3 tcvG(D_ / 32, D_ / 32);

    // fused QKV + 96-proj via one MFMA GEMM (N = 6272)
    convert_bf16<<<dim3((TD_ + 255) / 256), blk, 0, stream>>>(h, h_bf, (int)TD_);
    transpose_convert<<<tcvG, tcvB, 0, stream>>>(Wq, Wtc, D_, D_);
    transpose_convert<<<tcvG, tcvB, 0, stream>>>(Wk, Wtc + (size_t)D_ * D_, D_, D_);
    transpose_convert<<<tcvG, tcvB, 0, stream>>>(Wv, Wtc + (size_t)2 * D_ * D_, D_, D_);
    pack96<<<dim3(128, 8), blk, 0, stream>>>(Ww1, Wbt, Wg, Wtc + (size_t)3 * D_ * D_);
    mfma_gemm<3><<<dim3(6272 / 128, T_ / 128), blk, 0, stream>>>(
        h_bf, Wtc, qkv, s96, T_, 6272, D_);

    // gates + w path
    bg96<<<dim3(T_ * 128 / 256), blk, 0, stream>>>(s96, bbt, bgp, w1bf, betaB, Gb);
    scan_g<<<dim3(H_), blk, 0, stream>>>(Gb);
    transpose_convert<<<dim3(D_ / 32, 1), tcvB, 0, stream>>>(Ww2, Ww2t, 32, D_);
    mfma_gemm<0><<<dim3(D_ / 128, T_ / 128), blk, 0, stream>>>(
        w1bf, Ww2t, wr, nullptr, T_, D_, 32);
    conv_silu_norm<<<dim3(T_ * H_), dim3(64), 0, stream>>>(wr, convw, wh);

    int nChunks = H_ / NH;
    for (int c = 0; c < nChunks; c++) {
        int hs = c * NH;
        pairdotLC<<<dim3(NTRI_ * NH), blk, 0, stream>>>(kh, wh, betaB, ELb, Ct, hs, NH);
        diag_inv<<<dim3(16, NH), dim3(64), 0, stream>>>(ELb, Mv);
        solve_mfma<<<dim3(16 * NH), blk, 0, stream>>>(Ct, ELb, Mv, NH);
        pairdotE<<<dim3(NTRI_ * NH), blk, 0, stream>>>(qh, wh, betaB, ELb, hs, NH);
        flash_split<<<dim3(NTRI_ * NH), blk, 0, stream>>>(
            qh, kh, vt, ELb, Ct, Gb, OpB, mlB, hs, NH);
        combine<<<dim3(16, NH), blk, 0, stream>>>(OpB, mlB, of_bf, hs);
    }

    // out = of @ Wo via MFMA
    transpose_convert<<<tcvG, tcvB, 0, stream>>>(Wo, WoT, D_, D_);
    mfma_gemm<0><<<dim3(D_ / 128, T_ / 128), blk, 0, stream>>>(
        of_bf, WoT, out, nullptr, T_, D_, D_);
}

// Round 13
// 571.864 us; speedup vs baseline: 1.1834x; 1.1834x over previous
//
// PaTH attention — r13: REVERT flash_split to r11's LDS-staged E/C pipeline
// (r12's direct-from-global was 2.2x slower: C fragments are wave-replicated
// and the 1-deep pipeline can't hide scattered L2 latency) + deepen the
// register prefetch to 2-ahead with a third buffer set.
#include <hip/hip_runtime.h>
#include <hip/hip_bf16.h>

typedef __hip_bfloat16 bf16;
typedef unsigned short ushort_t;

#define T_  1024
#define D_  2048
#define H_  32
#define HD_ 64
#define NTRI_ 136   // 16*17/2 lower-triangular tile pairs

static const size_t TT_ = (size_t)T_ * T_;
static const size_t TD_ = (size_t)T_ * D_;

__device__ __forceinline__ ushort_t f2bf(float v) {
    bf16 b = __float2bfloat16(v);
    return *(ushort_t*)&b;
}
__device__ __forceinline__ float bf2f(ushort_t u) {
    bf16 b = *(bf16*)&u;
    return __bfloat162float(b);
}

// decode tri -> (st, tb) with tri = tb*(tb+1)/2 + st, st <= tb
__device__ __forceinline__ void tri_decode(int tri, int& st, int& tb) {
    int t = (int)((sqrtf(8.f * (float)tri + 1.f) - 1.f) * 0.5f);
    if (t * (t + 1) / 2 > tri) t--;
    if ((t + 1) * (t + 2) / 2 <= tri) t++;
    st = tri - t * (t + 1) / 2;
    tb = t;
}

// XCD-aware decode for (NTRI_, NH) grids flattened to 1-D: head z -> XCD z&7
// (MI355X round-robins consecutive blockIdx across 8 XCDs; keeping one head's
// blocks on one XCD makes its 2MB L/C/E panels L2-resident across consumers.)
__device__ __forceinline__ void swz_tri(int bid, int NH, int& tri, int& z) {
    if ((NH & 7) == 0) {
        int xcd = bid & 7, m = bid >> 3;
        z = xcd + 8 * (m / NTRI_);
        tri = m % NTRI_;
    } else {
        z = bid / NTRI_;
        tri = bid % NTRI_;
    }
}

typedef __attribute__((ext_vector_type(8))) short frag8;
typedef __attribute__((ext_vector_type(4))) float f32x4;
typedef __attribute__((ext_vector_type(4))) unsigned short u16x4;
typedef __attribute__((ext_vector_type(8))) unsigned short u16x8;

#define MFMA16(a, b, c) __builtin_amdgcn_mfma_f32_16x16x32_bf16((a), (b), (c), 0, 0, 0)

// ---------------------------------------------------------------------------
// MFMA GEMM: C = A[M,K]bf16 @ Bt[N,K]^T. 128x128 tile, BK=32.
// OUT: 0 = f32 row-major [M,N]
//      3 = packed QKV+small: col<2048 -> qh head-major bf16; <4096 -> kh;
//          <6144 -> vt transposed [head][64][T]; >=6144 -> Cout2 f32 [M][128]
// ---------------------------------------------------------------------------
template <int OUT>
__global__ __launch_bounds__(256) void mfma_gemm(
    const ushort_t* __restrict__ A, const ushort_t* __restrict__ Bt,
    void* __restrict__ Cout, void* __restrict__ Cout2, int M, int N, int K)
{
    __shared__ short Al[128 * 32];
    __shared__ short Bl[128 * 32];
    int tid = threadIdx.x;
    int w = tid >> 6, l = tid & 63;
    int row0 = blockIdx.y * 128, col0 = blockIdx.x * 128;
    int mq = (w >> 1) * 64, nq = (w & 1) * 64;
    int lm = l & 15, kq = l >> 4;
    f32x4 acc[4][4] = {};
    const ushort_t* Ap = A + (size_t)row0 * K;
    const ushort_t* Bp = Bt + (size_t)col0 * K;
    for (int kk = 0; kk < K; kk += 32) {
        __syncthreads();
#pragma unroll
        for (int r = 0; r < 2; r++) {
            int c = r * 256 + w * 64 + l;
            int row = c >> 2, kc = (c & 3) * 8;
            const ushort_t* ga = Ap + (size_t)row * K + kk + kc;
            const ushort_t* gb = Bp + (size_t)row * K + kk + kc;
            short* la = Al + (size_t)(r * 256 + w * 64) * 8;
            short* lb = Bl + (size_t)(r * 256 + w * 64) * 8;
            __builtin_amdgcn_global_load_lds((const __attribute__((address_space(1))) void*)ga,
                                             (__attribute__((address_space(3))) void*)la, 16, 0, 0);
            __builtin_amdgcn_global_load_lds((const __attribute__((address_space(1))) void*)gb,
                                             (__attribute__((address_space(3))) void*)lb, 16, 0, 0);
        }
        __builtin_amdgcn_s_waitcnt(0);
        __syncthreads();
        frag8 af[4], bfg[4];
#pragma unroll
        for (int i = 0; i < 4; i++)
            af[i] = *(const frag8*)&Al[(size_t)(mq + i * 16 + lm) * 32 + kq * 8];
#pragma unroll
        for (int j = 0; j < 4; j++)
            bfg[j] = *(const frag8*)&Bl[(size_t)(nq + j * 16 + lm) * 32 + kq * 8];
#pragma unroll
        for (int i = 0; i < 4; i++)
#pragma unroll
            for (int j = 0; j < 4; j++)
                acc[i][j] = MFMA16(af[i], bfg[j], acc[i][j]);
    }
#pragma unroll
    for (int i = 0; i < 4; i++)
#pragma unroll
        for (int j = 0; j < 4; j++)
#pragma unroll
            for (int r = 0; r < 4; r++) {
                int row = row0 + mq + i * 16 + kq * 4 + r;
                int col = col0 + nq + j * 16 + lm;
                float v = acc[i][j][r];
                if (OUT == 0) {
                    ((float*)Cout)[(size_t)row * N + col] = v;
                } else {
                    ushort_t* q = (ushort_t*)Cout;
                    int which = col >> 11, cl = col & 2047;
                    int hd = cl >> 6, d = cl & 63;
                    if (which == 0)
                        q[((size_t)hd * M + row) * 64 + d] = f2bf(v);
                    else if (which == 1)
                        q[(size_t)M * 2048 + ((size_t)hd * M + row) * 64 + d] = f2bf(v);
                    else if (which == 2)
                        q[(size_t)M * 4096 + ((size_t)hd * 64 + d) * M + row] = f2bf(v);
                    else
                        ((float*)Cout2)[(size_t)row * 128 + (col - 6144)] = v;
                }
            }
}

// ---------------------------------------------------------------------------
__global__ void transpose_convert(const float* __restrict__ W, ushort_t* __restrict__ Wt,
                                  int R, int Cc)
{
    __shared__ float tile[32][33];
    int bx = blockIdx.x * 32, by = blockIdx.y * 32;
    int tx = threadIdx.x, ty = threadIdx.y;
    for (int i = ty; i < 32; i += 8)
        tile[i][tx] = W[(size_t)(by + i) * Cc + bx + tx];
    __syncthreads();
    for (int i = ty; i < 32; i += 8)
        Wt[(size_t)(bx + i) * R + by + tx] = f2bf(tile[tx][i]);
}

// pack Ww1^T/Wbt^T/Wg^T (+zero pad) into rows [0..128) of dst[128][2048]
__global__ void pack96(const float* __restrict__ Ww1, const float* __restrict__ Wbt,
                       const float* __restrict__ Wg, ushort_t* __restrict__ dst)
{
    int r = blockIdx.x;
    int k = blockIdx.y * 256 + threadIdx.x;
    float v = 0.f;
    if (r < 32)       v = Ww1[(size_t)k * 32 + r];
    else if (r < 64)  v = Wbt[(size_t)k * 32 + (r - 32)];
    else if (r < 96)  v = Wg[(size_t)k * 32 + (r - 64)];
    dst[(size_t)r * 2048 + k] = f2bf(v);
}

__global__ void convert_bf16(const float* __restrict__ in, ushort_t* __restrict__ out, int n)
{
    int i = blockIdx.x * 256 + threadIdx.x;
    if (i < n) out[i] = f2bf(in[i]);
}

// epilogue of the 96-proj: w1 bf16, beta, G(pre-scan)
__global__ void bg96(const float* __restrict__ s96, const float* __restrict__ bbt,
                     const float* __restrict__ bgp, ushort_t* __restrict__ w1bf,
                     float* __restrict__ betaB, float* __restrict__ Gb)
{
    int idx = blockIdx.x * 256 + threadIdx.x;   // over T_*128
    int t = idx >> 7, o = idx & 127;
    if (o >= 96) return;
    float v = s96[(size_t)t * 128 + o];
    if (o < 32) {
        w1bf[(size_t)t * 32 + o] = f2bf(v);
    } else if (o < 64) {
        float xb = v + bbt[o - 32];
        betaB[(size_t)t * H_ + (o - 32)] = 2.f / (1.f + expf(-xb));
    } else {
        float xg = v + bgp[o - 64];
        Gb[(size_t)t * H_ + (o - 64)] =
            (xg >= 0.f) ? -log1pf(expf(-xg)) : (xg - log1pf(expf(xg)));
    }
}

// parallel inclusive scan of G[:, h] per head. Grid (H_), block 256.
__global__ void scan_g(float* __restrict__ G)
{
    int h = blockIdx.x;
    int tid = threadIdx.x;
    __shared__ float psum[256];
    float v[4];
    float s = 0.f;
#pragma unroll
    for (int r = 0; r < 4; r++) {
        v[r] = G[(size_t)(tid * 4 + r) * H_ + h];
        s += v[r];
    }
    psum[tid] = s;
    __syncthreads();
    for (int off = 1; off < 256; off <<= 1) {
        float t = (tid >= off) ? psum[tid - off] : 0.f;
        __syncthreads();
        psum[tid] += t;
        __syncthreads();
    }
    float run = (tid > 0) ? psum[tid - 1] : 0.f;
#pragma unroll
    for (int r = 0; r < 4; r++) {
        run += v[r];
        G[(size_t)(tid * 4 + r) * H_ + h] = run;
    }
}

// conv(3) + silu + l2norm -> wh bf16 head-major [H][T][64]
__global__ void conv_silu_norm(const float* __restrict__ wr, const float* __restrict__ convw,
                               ushort_t* __restrict__ wh)
{
    int b = blockIdx.x;
    int t = b >> 5, h = b & 31;
    int d = threadIdx.x;
    int c = h * 64 + d;
    float c0 = convw[c * 3 + 0];
    float c1 = convw[c * 3 + 1];
    float c2 = convw[c * 3 + 2];
    float x = c2 * wr[(size_t)t * D_ + c];
    if (t >= 1) x += c1 * wr[(size_t)(t - 1) * D_ + c];
    if (t >= 2) x += c0 * wr[(size_t)(t - 2) * D_ + c];
    float y = x / (1.f + expf(-x));
    float ss = y * y;
    for (int off = 32; off > 0; off >>= 1) ss += __shfl_xor(ss, off, 64);
    wh[((size_t)h * T_ + t) * 64 + d] = f2bf(y * rsqrtf(ss));
}

// ---------------------------------------------------------------------------
// pairdotLC: per lower tile (t0,s0):
//   L[t][s]  = strict(w_t.w_s)*beta[s]   (bf16 row-major, into ELb)
//   Ct[s][t] = strict(w_t.k_s)           (bf16 TRANSPOSED [s][t])
// Grid (NTRI_*NH) 1-D, XCD-swizzled.
// ---------------------------------------------------------------------------
__global__ __launch_bounds__(256) void pairdotLC(
    const ushort_t* __restrict__ kh, const ushort_t* __restrict__ wh,
    const float* __restrict__ betaB,
    ushort_t* __restrict__ ELb, ushort_t* __restrict__ Ct, int hs, int NH)
{
    int st, tb, tri, z;
    swz_tri(blockIdx.x, NH, tri, z);
    tri_decode(tri, st, tb);
    int s0 = st * 64, t0 = tb * 64;
    int head = hs + z;
    const ushort_t* kb = kh + (size_t)head * T_ * 64;
    const ushort_t* wb = wh + (size_t)head * T_ * 64;
    ushort_t* Lz = ELb + (size_t)z * TT_;
    ushort_t* Cz = Ct + (size_t)z * TT_;
    int tid = threadIdx.x;
    int w = tid >> 6, l = tid & 63;
    int lm = l & 15, kq = l >> 4;
    int rowA = t0 + w * 16 + lm;
    f32x4 accL[4] = {}, accS[4] = {};
#pragma unroll
    for (int kk = 0; kk < 64; kk += 32) {
        frag8 aw = *(const frag8*)&wb[(size_t)rowA * 64 + kk + kq * 8];
#pragma unroll
        for (int j = 0; j < 4; j++) {
            int colr = s0 + j * 16 + lm;
            frag8 bw = *(const frag8*)&wb[(size_t)colr * 64 + kk + kq * 8];
            frag8 bk = *(const frag8*)&kb[(size_t)colr * 64 + kk + kq * 8];
            accL[j] = MFMA16(aw, bw, accL[j]);
            accS[j] = MFMA16(aw, bk, accS[j]);
        }
    }
    int m0 = w * 16 + kq * 4;
#pragma unroll
    for (int j = 0; j < 4; j++) {
        int s = s0 + j * 16 + lm;
        float beta = betaB[(size_t)s * H_ + head];
        ushort_t cl[4];
#pragma unroll
        for (int r = 0; r < 4; r++) {
            int t = t0 + m0 + r;
            Lz[(size_t)t * T_ + s] = f2bf((s < t) ? accL[j][r] * beta : 0.f);
            cl[r] = f2bf((s < t) ? accS[j][r] : 0.f);
        }
        *(u16x4*)&Cz[(size_t)s * T_ + t0 + m0] = *(u16x4*)cl;
    }
}

// pairdotE: Em[t][s] = -causal(q_t.w_s)*beta[s] into ELb (L dead post-solve)
// Grid (NTRI_*NH) 1-D, XCD-swizzled.
__global__ __launch_bounds__(256) void pairdotE(
    const ushort_t* __restrict__ qh, const ushort_t* __restrict__ wh,
    const float* __restrict__ betaB, ushort_t* __restrict__ ELb, int hs, int NH)
{
    int st, tb, tri, z;
    swz_tri(blockIdx.x, NH, tri, z);
    tri_decode(tri, st, tb);
    int s0 = st * 64, t0 = tb * 64;
    int head = hs + z;
    const ushort_t* qb = qh + (size_t)head * T_ * 64;
    const ushort_t* wb = wh + (size_t)head * T_ * 64;
    ushort_t* Ez = ELb + (size_t)z * TT_;
    int tid = threadIdx.x;
    int w = tid >> 6, l = tid & 63;
    int lm = l & 15, kq = l >> 4;
    int rowA = t0 + w * 16 + lm;
    f32x4 accE[4] = {};
#pragma unroll
    for (int kk = 0; kk < 64; kk += 32) {
        frag8 aq = *(const frag8*)&qb[(size_t)rowA * 64 + kk + kq * 8];
#pragma unroll
        for (int j = 0; j < 4; j++) {
            frag8 bw = *(const frag8*)&wb[(size_t)(s0 + j * 16 + lm) * 64 + kk + kq * 8];
            accE[j] = MFMA16(aq, bw, accE[j]);
        }
    }
    int m0 = w * 16 + kq * 4;
#pragma unroll
    for (int j = 0; j < 4; j++) {
        int s = s0 + j * 16 + lm;
        float beta = betaB[(size_t)s * H_ + head];
#pragma unroll
        for (int r = 0; r < 4; r++) {
            int t = t0 + m0 + r;
            Ez[(size_t)t * T_ + s] = f2bf((s <= t) ? -accE[j][r] * beta : 0.f);
        }
    }
}

// ---------------------------------------------------------------------------
// diag_inv: invert 64x64 unit-lower diag blocks of (I + L); Minv bf16 out.
// Column-sweep forward substitution, fully unrolled so each thread's column
// x[64] lives in VGPRs. Grid (16, NH), block 64.
// ---------------------------------------------------------------------------
__global__ void diag_inv(const ushort_t* __restrict__ Lb, ushort_t* __restrict__ Minv)
{
    int bi = blockIdx.x, z = blockIdx.y;
    const ushort_t* Lh = Lb + (size_t)z * TT_;
    __shared__ float NbT[64][65];      // NbT[c][r] = N[r][c]
    int j = threadIdx.x;
    for (int i = j; i < 4096; i += 64) {
        int r = i >> 6, c = i & 63;    // c == j: coalesced row reads
        NbT[c][r] = (c < r) ? bf2f(Lh[(size_t)(bi * 64 + r) * T_ + bi * 64 + c]) : 0.f;
    }
    __syncthreads();
    // column j of X = (I+N)^{-1}:  x[t] = d(t,j) - sum_{i<t} N[t][i] x[i]
    float x[64];
#pragma unroll
    for (int t = 0; t < 64; t++) x[t] = (t == j) ? 1.f : 0.f;
#pragma unroll
    for (int i = 0; i < 63; i++) {
        float xi = x[i];
#pragma unroll
        for (int t = i + 1; t < 64; t++) x[t] -= NbT[i][t] * xi;
    }
    ushort_t* Mo = Minv + ((size_t)z * 16 + bi) * 4096;
#pragma unroll
    for (int t = 0; t < 64; t++) Mo[t * 64 + j] = f2bf(x[t]);   // coalesced
}

// ---------------------------------------------------------------------------
// solve_mfma: block-forward solve for one 64-col strip, C-resident-in-LDS,
// L A-fragments DIRECT FROM GLOBAL (L2-hot via XCD swizzle), 4-deep register
// pipeline, no barriers in the K-loop (2/step around the Xbt round-trip).
// Grid (16*NH) 1-D, block 256. LDS = 132 + 9 = 141KB (1 block/CU).
// ---------------------------------------------------------------------------
__global__ __launch_bounds__(256) void solve_mfma(
    ushort_t* __restrict__ Ct, const ushort_t* __restrict__ Lb,
    const ushort_t* __restrict__ Minv, int NH)
{
    int bid = blockIdx.x;
    int ct, z;
    if ((NH & 7) == 0) {
        int xcd = bid & 7, m = bid >> 3, nh8 = NH >> 3;
        z = xcd + 8 * (m % nh8);
        ct = m / nh8;
    } else {
        z = bid % NH;
        ct = bid / NH;
    }
    ushort_t* Cz = Ct + (size_t)z * TT_;
    const ushort_t* Lz = Lb + (size_t)z * TT_;
    __shared__ ushort_t Cs[64][1032];   // strip's C panel, abs-col indexed, +8 pad
    __shared__ ushort_t Xbt[64][72];
    int tid = threadIdx.x;
    int w = tid >> 6, l = tid & 63;
    int lm = l & 15, kq = l >> 4;
    int s0 = ct * 64;
    int m0 = w * 16 + kq * 4;

    // DMA the strip's C rows into LDS, 1024B segments, cols >= 512*(s0>>9)
    {
        int h0 = s0 >> 9, segs = 2 - h0;
        for (int sg = w; sg < 64 * segs; sg += 4) {
            int r, hh;
            if (segs == 2) { r = sg >> 1; hh = sg & 1; }
            else           { r = sg;      hh = 1;      }
            const ushort_t* ga = Cz + (size_t)(s0 + r) * T_ + hh * 512 + l * 8;
            ushort_t* la = &Cs[r][hh * 512];
            __builtin_amdgcn_global_load_lds((const __attribute__((address_space(1))) void*)ga,
                                             (__attribute__((address_space(3))) void*)la, 16, 0, 0);
        }
    }
    __builtin_amdgcn_s_waitcnt(0);
    __syncthreads();

    for (int bi = ct; bi < 16; bi++) {
        int kend = bi * 64;   // also the L block-row base for this step
        const ushort_t* Lrow = Lz + (size_t)(kend + w * 16 + lm) * T_ + kq * 8;
        auto loadL = [&](int idx) -> frag8 {
            return *(const frag8*)&Lrow[s0 + idx * 32];
        };
        f32x4 acc[4] = {};
        auto mfma4 = [&](frag8 a, int idx) {
            int kk = s0 + idx * 32;
#pragma unroll
            for (int j = 0; j < 4; j++) {
                frag8 b = *(const frag8*)&Cs[j * 16 + lm][kk + kq * 8];
                acc[j] = MFMA16(a, b, acc[j]);
            }
        };

        const ushort_t* Mo = Minv + ((size_t)z * 16 + bi) * 4096;
        frag8 ma0 = *(const frag8*)&Mo[(size_t)(w * 16 + lm) * 64 + kq * 8];
        frag8 ma1 = *(const frag8*)&Mo[(size_t)(w * 16 + lm) * 64 + 32 + kq * 8];
        u16x4 rhs[4];
#pragma unroll
        for (int j = 0; j < 4; j++)
            rhs[j] = *(const u16x4*)&Cs[j * 16 + lm][kend + m0];

        // K-loop: nk = 2*(bi-ct) chunks of 32, 4-deep register pipeline,
        // no barriers (reads Cs cols<kend; writes this step go to col bi).
        int nk = (kend - s0) >> 5;
        frag8 p0, p1, p2, p3;
        if (nk > 0) p0 = loadL(0);
        if (nk > 1) p1 = loadL(1);
        if (nk > 2) p2 = loadL(2);
        if (nk > 3) p3 = loadL(3);
        int i = 0;
        for (; i + 4 <= nk; i += 4) {
            frag8 c0 = p0, c1 = p1, c2 = p2, c3 = p3;
            if (i + 4 < nk) p0 = loadL(i + 4);
            if (i + 5 < nk) p1 = loadL(i + 5);
            if (i + 6 < nk) p2 = loadL(i + 6);
            if (i + 7 < nk) p3 = loadL(i + 7);
            mfma4(c0, i); mfma4(c1, i + 1); mfma4(c2, i + 2); mfma4(c3, i + 3);
        }
        if (i < nk) {       // tail of 2 (nk is even)
            mfma4(p0, i);
            mfma4(p1, i + 1);
        }

        // epilogue: X = rhs - acc -> Xbt; res = Minv_diag @ X -> Cs col bi
#pragma unroll
        for (int j = 0; j < 4; j++) {
            ushort_t xb[4];
#pragma unroll
            for (int r = 0; r < 4; r++) xb[r] = f2bf(bf2f(rhs[j][r]) - acc[j][r]);
            *(u16x4*)&Xbt[j * 16 + lm][m0] = *(u16x4*)xb;
        }
        __syncthreads();                       // Xbt writes visible
        f32x4 res[4] = {};
#pragma unroll
        for (int j = 0; j < 4; j++) {
            frag8 b0 = *(const frag8*)&Xbt[j * 16 + lm][kq * 8];
            frag8 b1 = *(const frag8*)&Xbt[j * 16 + lm][32 + kq * 8];
            res[j] = MFMA16(ma0, b0, res[j]);
            res[j] = MFMA16(ma1, b1, res[j]);
        }
#pragma unroll
        for (int j = 0; j < 4; j++) {
            ushort_t cr[4];
#pragma unroll
            for (int r = 0; r < 4; r++) cr[r] = f2bf(res[j][r]);
            *(u16x4*)&Cs[j * 16 + lm][kend + m0] = *(u16x4*)cr;
        }
        __syncthreads();   // Cs col-bi + Xbt reuse ordered for next step
    }

    // writeback cols [s0, 1024) of the strip
    int nW = (1024 - s0) >> 3;
    for (int i = tid; i < 64 * nW; i += 256) {
        int r = i / nW, c = (i - r * nW) * 8;
        *(u16x8*)&Cz[(size_t)(s0 + r) * T_ + s0 + c] = *(const u16x8*)&Cs[r][s0 + c];
    }
}

// ---------------------------------------------------------------------------
// flash_split: one triangular (s-tile, t-tile, head) per block.
//   x = q.k^T + sum_k Em[t,k] C[k,s]; single-tile softmax partial -> Op/ml.
// K/V/q fragments direct from global; E/C chunks LDS-staged with a 2-AHEAD
// (triple-buffer) register prefetch. Grid (NTRI_*NH) 1-D, XCD-swizzled.
// ---------------------------------------------------------------------------
__global__ __launch_bounds__(256) void flash_split(
    const ushort_t* __restrict__ qh, const ushort_t* __restrict__ kh,
    const ushort_t* __restrict__ vt, const ushort_t* __restrict__ Em,
    const ushort_t* __restrict__ Ct, const float* __restrict__ Gb,
    ushort_t* __restrict__ Op, float* __restrict__ ml, int hs, int NH)
{
    int st, tb, tri, z;
    swz_tri(blockIdx.x, NH, tri, z);
    tri_decode(tri, st, tb);
    int t0 = tb * 64, s0 = st * 64;
    int head = hs + z;
    const ushort_t* qb = qh + (size_t)head * T_ * 64;
    const ushort_t* kb = kh + (size_t)head * T_ * 64;
    const ushort_t* vb = vt + (size_t)head * 64 * T_;
    const ushort_t* Ez = Em + (size_t)z * TT_;
    const ushort_t* Cz = Ct + (size_t)z * TT_;
    __shared__ ushort_t El[64][72];
    __shared__ ushort_t Cl[64][72];
    __shared__ ushort_t Pl[4][16][76];
    int tid = threadIdx.x;
    int w = tid >> 6, l = tid & 63;
    int lm = l & 15, kq = l >> 4;
    int rowA = t0 + w * 16 + lm;
    int m0 = w * 16 + kq * 4;

    u16x8 eA[2], cA[2], eB[2], cB[2], eC[2], cC[2];
    auto issueEC = [&](u16x8 (&re)[2], u16x8 (&rc)[2], int kc) {
#pragma unroll
        for (int t = 0; t < 2; t++) {
            int i = tid + t * 256;
            int r = i >> 3, cc = (i & 7) * 8;
            re[t] = *(const u16x8*)&Ez[(size_t)(t0 + r) * T_ + kc + cc];
            rc[t] = *(const u16x8*)&Cz[(size_t)(s0 + r) * T_ + kc + cc];
        }
    };
    auto stageEC = [&](u16x8 (&re)[2], u16x8 (&rc)[2]) {
#pragma unroll
        for (int t = 0; t < 2; t++) {
            int i = tid + t * 256;
            int r = i >> 3, cc = (i & 7) * 8;
            *(u16x8*)&El[r][cc] = re[t];
            *(u16x8*)&Cl[r][cc] = rc[t];
        }
    };
    auto mfmaEC = [&](f32x4 (&x)[4]) {
#pragma unroll
        for (int kk2 = 0; kk2 < 64; kk2 += 32) {
            frag8 a = *(const frag8*)&El[w * 16 + lm][kk2 + kq * 8];
#pragma unroll
            for (int j = 0; j < 4; j++) {
                frag8 b = *(const frag8*)&Cl[j * 16 + lm][kk2 + kq * 8];
                x[j] = MFMA16(a, b, x[j]);
            }
        }
    };

    int nc = tb - st + 1;
    // prefetch chunks 0 and 1 so latency hides under QK^T
    issueEC(eA, cA, s0);
    if (nc > 1) issueEC(eB, cB, s0 + 64);

    // q and K fragments direct from global
    frag8 aq0 = *(const frag8*)&qb[(size_t)rowA * 64 + kq * 8];
    frag8 aq1 = *(const frag8*)&qb[(size_t)rowA * 64 + 32 + kq * 8];
    f32x4 x[4] = {};
#pragma unroll
    for (int j = 0; j < 4; j++) {
        frag8 b0 = *(const frag8*)&kb[(size_t)(s0 + j * 16 + lm) * 64 + kq * 8];
        frag8 b1 = *(const frag8*)&kb[(size_t)(s0 + j * 16 + lm) * 64 + 32 + kq * 8];
        x[j] = MFMA16(aq0, b0, x[j]);
        x[j] = MFMA16(aq1, b1, x[j]);
    }

    // correction loop: 3-phase rotation, each chunk's loads get a full
    // iteration (2 barriers + stage + MFMA burst) of slack to land.
    int ci = 0;
    for (;;) {
        __syncthreads();
        stageEC(eA, cA);
        if (ci + 2 < nc) issueEC(eC, cC, s0 + (ci + 2) * 64);
        __syncthreads();
        mfmaEC(x);
        ci++; if (ci >= nc) break;

        __syncthreads();
        stageEC(eB, cB);
        if (ci + 2 < nc) issueEC(eA, cA, s0 + (ci + 2) * 64);
        __syncthreads();
        mfmaEC(x);
        ci++; if (ci >= nc) break;

        __syncthreads();
        stageEC(eC, cC);
        if (ci + 2 < nc) issueEC(eB, cB, s0 + (ci + 2) * 64);
        __syncthreads();
        mfmaEC(x);
        ci++; if (ci >= nc) break;
    }

    // V fragments direct from global; latency hides under softmax VALU
    frag8 vf0[4], vf1[4];
#pragma unroll
    for (int j = 0; j < 4; j++) {
        vf0[j] = *(const frag8*)&vb[(size_t)(j * 16 + lm) * T_ + s0 + kq * 8];
        vf1[j] = *(const frag8*)&vb[(size_t)(j * 16 + lm) * T_ + s0 + 32 + kq * 8];
    }

    // single-tile softmax partial
    float lg[4][4];
#pragma unroll
    for (int j = 0; j < 4; j++) {
        int s = s0 + j * 16 + lm;
        float g = Gb[(size_t)s * H_ + head];
#pragma unroll
        for (int r = 0; r < 4; r++) {
            int t = t0 + m0 + r;
            lg[j][r] = (s <= t) ? (x[j][r] * 0.125f - g) : -1e30f;
        }
    }
    float mrow[4];
#pragma unroll
    for (int r = 0; r < 4; r++)
        mrow[r] = fmaxf(fmaxf(lg[0][r], lg[1][r]), fmaxf(lg[2][r], lg[3][r]));
#pragma unroll
    for (int d = 1; d < 16; d <<= 1)
#pragma unroll
        for (int r = 0; r < 4; r++) mrow[r] = fmaxf(mrow[r], __shfl_xor(mrow[r], d, 64));
    float lrow[4] = {0.f, 0.f, 0.f, 0.f};
#pragma unroll
    for (int j = 0; j < 4; j++)
#pragma unroll
        for (int r = 0; r < 4; r++) {
            float p = __expf(lg[j][r] - mrow[r]);
            lg[j][r] = p;
            lrow[r] += p;
        }
#pragma unroll
    for (int d = 1; d < 16; d <<= 1)
#pragma unroll
        for (int r = 0; r < 4; r++) lrow[r] += __shfl_xor(lrow[r], d, 64);
    // P -> per-wave slab (same-wave ordering, no barrier), O = P @ V
#pragma unroll
    for (int j = 0; j < 4; j++)
#pragma unroll
        for (int r = 0; r < 4; r++)
            Pl[w][kq * 4 + r][j * 16 + lm] = f2bf(lg[j][r]);
    f32x4 o[4] = {};
#pragma unroll
    for (int j = 0; j < 4; j++) {
        frag8 a0 = *(const frag8*)&Pl[w][lm][kq * 8];
        frag8 a1 = *(const frag8*)&Pl[w][lm][32 + kq * 8];
        o[j] = MFMA16(a0, vf0[j], o[j]);
        o[j] = MFMA16(a1, vf1[j], o[j]);
    }
    size_t pbase = ((size_t)z * NTRI_ + tri) * 4096;
#pragma unroll
    for (int j = 0; j < 4; j++)
#pragma unroll
        for (int r = 0; r < 4; r++)
            Op[pbase + (size_t)(m0 + r) * 64 + j * 16 + lm] = f2bf(o[j][r]);
    if (lm == 0) {
        size_t mbase = ((size_t)z * NTRI_ + tri) * 128;
#pragma unroll
        for (int r = 0; r < 4; r++) {
            ml[mbase + m0 + r] = mrow[r];
            ml[mbase + 64 + m0 + r] = lrow[r];
        }
    }
}

// ---------------------------------------------------------------------------
// combine: merge <=16 partials per (t-tile, head) -> of bf16.
// ---------------------------------------------------------------------------
__global__ __launch_bounds__(256) void combine(
    const ushort_t* __restrict__ Op, const float* __restrict__ ml,
    ushort_t* __restrict__ of, int hs)
{
    int tb = blockIdx.x, z = blockIdx.y;
    int head = hs + z;
    int tid = threadIdx.x;
    int row = tid >> 2, cg = (tid & 3) * 16;
    size_t pb0 = (size_t)z * NTRI_ + (size_t)tb * (tb + 1) / 2;
    float M = -1e30f;
    for (int st = 0; st <= tb; st++)
        M = fmaxf(M, ml[(pb0 + st) * 128 + row]);
    float acc[16] = {};
    float lsum = 0.f;
    for (int st = 0; st <= tb; st++) {
        float mp = ml[(pb0 + st) * 128 + row];
        float lp = ml[(pb0 + st) * 128 + 64 + row];
        float sc = __expf(mp - M);
        lsum += lp * sc;
        const ushort_t* op = Op + (pb0 + st) * 4096 + (size_t)row * 64 + cg;
#pragma unroll
        for (int i = 0; i < 16; i++) acc[i] += bf2f(op[i]) * sc;
    }
    float inv = 1.f / lsum;
    int t = tb * 64 + row;
    ushort_t* dst = of + (size_t)t * D_ + (size_t)head * 64 + cg;
#pragma unroll
    for (int i = 0; i < 16; i++) dst[i] = f2bf(acc[i] * inv);
}

// ---------------------------------------------------------------------------
extern "C" void kernel_launch(void* const* d_in, const int* in_sizes, int n_in,
                              void* d_out, int out_size, void* d_ws, size_t ws_size,
                              hipStream_t stream)
{
    const float* h     = (const float*)d_in[0];
    const float* Wq    = (const float*)d_in[1];
    const float* Wk    = (const float*)d_in[2];
    const float* Wv    = (const float*)d_in[3];
    const float* Ww1   = (const float*)d_in[4];
    const float* Ww2   = (const float*)d_in[5];
    const float* convw = (const float*)d_in[6];
    const float* Wbt   = (const float*)d_in[7];
    const float* bbt   = (const float*)d_in[8];
    const float* Wg    = (const float*)d_in[9];
    const float* bgp   = (const float*)d_in[10];
    const float* Wo    = (const float*)d_in[11];
    float* out = (float*)d_out;

    float* ws = (float*)d_ws;
    size_t off = 0;
    auto allocF = [&](size_t nf) { float* p = ws + off; off += (nf + 1023) & ~(size_t)1023; return p; };

    // ---- persistent region (lives across the whole launch) ----
    float*    betaB = allocF((size_t)T_ * H_);
    float*    Gb    = allocF((size_t)T_ * H_);
    ushort_t* h_bf  = (ushort_t*)allocF(TD_ / 2);   // reused as of_bf after QKV GEMM
    ushort_t* of_bf = h_bf;
    ushort_t* w1bf  = (ushort_t*)allocF((size_t)T_ * 32 / 2);
    ushort_t* Ww2t  = (ushort_t*)allocF((size_t)D_ * 32 / 2);
    ushort_t* qkv   = (ushort_t*)allocF((size_t)3 * TD_ / 2);
    ushort_t* qh    = qkv;
    ushort_t* kh    = qkv + TD_;
    ushort_t* vt    = qkv + 2 * TD_;
    ushort_t* wh    = (ushort_t*)allocF(TD_ / 2);

    size_t scrOff = off;            // start of the overlaid scratch region
    size_t capF = ws_size / 4;

    // ---- phase A scratch (projection prep; dead before the chunk loop) ----
    float*    wr  = allocF(TD_);
    float*    s96 = allocF((size_t)T_ * 128);
    ushort_t* Wtc = (ushort_t*)allocF((size_t)6272 * D_ / 2);   // QKV + 96-pack

    // ---- phase B scratch overlays phase A (per-head chunk buffers) ----
    int NH = 32;
    ushort_t *ELb, *Ct, *OpB, *Mv;
    float* mlB;
    for (;;) {
        off = scrOff;
        ELb = (ushort_t*)allocF((size_t)NH * TT_ / 2);            // L, then Em
        Ct  = (ushort_t*)allocF((size_t)NH * TT_ / 2);
        OpB = (ushort_t*)allocF((size_t)NH * NTRI_ * 4096 / 2);   // triangular partials
        Mv  = (ushort_t*)allocF((size_t)NH * 16 * 4096 / 2);
        mlB = allocF((size_t)NH * NTRI_ * 128);
        if (off <= capF || NH == 1) break;
        NH >>= 1;
    }

    // ---- phase C scratch: Wo^T overlays phase B (all per-head dead) ----
    ushort_t* WoT = (ushort_t*)(ws + scrOff);

    dim3 blk(256);
    dim3 tcvB(32, 8);
    dim3 tcvG(D_ / 32, D_ / 32);

    // fused QKV + 96-proj via one MFMA GEMM (N = 6272)
    convert_bf16<<<dim3((TD_ + 255) / 256), blk, 0, stream>>>(h, h_bf, (int)TD_);
    transpose_convert<<<tcvG, tcvB, 0, stream>>>(Wq, Wtc, D_, D_);
    transpose_convert<<<tcvG, tcvB, 0, stream>>>(Wk, Wtc + (size_t)D_ * D_, D_, D_);
    transpose_convert<<<tcvG, tcvB, 0, stream>>>(Wv, Wtc + (size_t)2 * D_ * D_, D_, D_);
    pack96<<<dim3(128, 8), blk, 0, stream>>>(Ww1, Wbt, Wg, Wtc + (size_t)3 * D_ * D_);
    mfma_gemm<3><<<dim3(6272 / 128, T_ / 128), blk, 0, stream>>>(
        h_bf, Wtc, qkv, s96, T_, 6272, D_);

    // gates + w path
    bg96<<<dim3(T_ * 128 / 256), blk, 0, stream>>>(s96, bbt, bgp, w1bf, betaB, Gb);
    scan_g<<<dim3(H_), blk, 0, stream>>>(Gb);
    transpose_convert<<<dim3(D_ / 32, 1), tcvB, 0, stream>>>(Ww2, Ww2t, 32, D_);
    mfma_gemm<0><<<dim3(D_ / 128, T_ / 128), blk, 0, stream>>>(
        w1bf, Ww2t, wr, nullptr, T_, D_, 32);
    conv_silu_norm<<<dim3(T_ * H_), dim3(64), 0, stream>>>(wr, convw, wh);

    int nChunks = H_ / NH;
    for (int c = 0; c < nChunks; c++) {
        int hs = c * NH;
        pairdotLC<<<dim3(NTRI_ * NH), blk, 0, stream>>>(kh, wh, betaB, ELb, Ct, hs, NH);
        diag_inv<<<dim3(16, NH), dim3(64), 0, stream>>>(ELb, Mv);
        solve_mfma<<<dim3(16 * NH), blk, 0, stream>>>(Ct, ELb, Mv, NH);
        pairdotE<<<dim3(NTRI_ * NH), blk, 0, stream>>>(qh, wh, betaB, ELb, hs, NH);
        flash_split<<<dim3(NTRI_ * NH), blk, 0, stream>>>(
            qh, kh, vt, ELb, Ct, Gb, OpB, mlB, hs, NH);
        combine<<<dim3(16, NH), blk, 0, stream>>>(OpB, mlB, of_bf, hs);
    }

    // out = of @ Wo via MFMA
    transpose_convert<<<tcvG, tcvB, 0, stream>>>(Wo, WoT, D_, D_);
    mfma_gemm<0><<<dim3(D_ / 128, T_ / 128), blk, 0, stream>>>(
        of_bf, WoT, out, nullptr, T_, D_, D_);
}